// Round 7
// baseline (737.817 us; speedup 1.0000x reference)
//
#include <hip/hip_runtime.h>
#include <math.h>

#define SEQ 2048
#define DMODEL 1024
#define NHEADS 16
#define DHEAD 64

// lmin sharding: 64 slices per head, each slice on its own 128B line
#define LSLOTS 64
#define LSTRIDE 32   // uints between slots (128 bytes)

typedef long long i64;
typedef unsigned short u16;
typedef __attribute__((ext_vector_type(4))) float f32x4;
typedef __attribute__((ext_vector_type(8))) short bf16x8;

#define IN_E  2097152   // 2048*1024
#define W_E   1048576   // 1024*1024
#define HEAD_E 131072   // 2048*64

// ---------------------------------------------------------------------------
// bf16 split helpers
// ---------------------------------------------------------------------------
__device__ inline u16 f2bf(float x) {                // RNE
    union { float f; unsigned u; } v; v.f = x;
    unsigned r = v.u + 0x7FFF + ((v.u >> 16) & 1);
    return (u16)(r >> 16);
}
__device__ inline float bf2f(u16 h) {
    union { unsigned u; float f; } v; v.u = ((unsigned)h) << 16;
    return v.f;
}

__device__ inline void gload16(const void* g, void* l) {
    __builtin_amdgcn_global_load_lds(
        (const __attribute__((address_space(1))) unsigned int*)g,
        (__attribute__((address_space(3))) unsigned int*)l, 16, 0, 0);
}

// ---------------------------------------------------------------------------
// Split 8 f32 arrays into bf16 hi/lo. z = array id, float4 per thread.
// ---------------------------------------------------------------------------
struct SplitArgs {
    const float* src[8];
    u16* dh[8];
    u16* dl[8];
    int n4[8];
};
__global__ __launch_bounds__(256)
void split_all(SplitArgs a)
{
    const int z = blockIdx.y;
    const int i = blockIdx.x * 256 + threadIdx.x;
    if (i >= a.n4[z]) return;
    const float4 x = ((const float4*)a.src[z])[i];
    u16 h0 = f2bf(x.x), h1 = f2bf(x.y), h2 = f2bf(x.z), h3 = f2bf(x.w);
    u16 l0 = f2bf(x.x - bf2f(h0)), l1 = f2bf(x.y - bf2f(h1));
    u16 l2 = f2bf(x.z - bf2f(h2)), l3 = f2bf(x.w - bf2f(h3));
    uint2 hh; hh.x = (unsigned)h0 | ((unsigned)h1 << 16); hh.y = (unsigned)h2 | ((unsigned)h3 << 16);
    uint2 ll; ll.x = (unsigned)l0 | ((unsigned)l1 << 16); ll.y = (unsigned)l2 | ((unsigned)l3 << 16);
    ((uint2*)a.dh[z])[i] = hh;
    ((uint2*)a.dl[z])[i] = ll;
}

// ---------------------------------------------------------------------------
// rel_enc computed + split directly
// ---------------------------------------------------------------------------
__global__ __launch_bounds__(256)
void posenc_split(u16* __restrict__ dh, u16* __restrict__ dl)
{
    const int idx = blockIdx.x * 256 + threadIdx.x;
    const int f = idx >> 10;
    const int i = idx & 1023;
    const float P = (float)(SEQ - 1 - f);
    const float ex = (float)(i & ~1) * (1.f / 1024.f);
    const float dv = powf(10000.f, -ex);
    const float ang = P * dv;
    const float val = (i & 1) ? cosf(ang) : sinf(ang);
    const u16 hb = f2bf(val);
    dh[idx] = hb;
    dl[idx] = f2bf(val - bf2f(hb));
}

// ---------------------------------------------------------------------------
// Split-3 bf16 MFMA TN GEMM, 128x128 tile, BK=32.
// C = A(MxK) * B(NxK)^T ; A/B pre-split into bf16 hi/lo.
// mode 0: f32 store C[z*sCz + m*ldc + n]
// mode 1: projection epilogue: head-layout split store to O1 (+bias1 if z==0);
//         if z==0 also O2 = acc + bias2 (split).
// mode 2: exact-GELU f32 store
// mode 3: BDhat -> PRE-SHIFTED score layout (rel_enc_shift applied at store):
//         elem [r][f]: if f >= SEQ-1-r  -> C[r][f+r-(SEQ-1)]
//                      else if r >= 1   -> C[r-1][f+r+1]
//         Holes [i][i+1] (never scatter targets) zeroed by n0==0 blocks.
// mode 5: score-finish in-place: C[r][c] = (acc + C[r][c])*0.03125 + msk[r][c]
//         (C holds pre-shifted BD from a prior mode-3 dispatch)
// ---------------------------------------------------------------------------
struct TNArgs {
    const u16 *Ah, *Al, *Bh, *Bl;
    i64 sAz, sBz;
    float* Cf; i64 sCz; int ldc;
    u16 *O1h, *O1l, *O2h, *O2l;
    const float *b1, *b2;
    const float *msk;
    int K, mode;
};

__global__ __launch_bounds__(256)
void mfma_tn128(TNArgs p)
{
    __shared__ __align__(16) u16 Ash[128 * 32];
    __shared__ __align__(16) u16 Asl[128 * 32];
    __shared__ __align__(16) u16 Bsh[128 * 32];
    __shared__ __align__(16) u16 Bsl[128 * 32];
    const int tid = threadIdx.x, wave = tid >> 6, lane = tid & 63;
    const int z = blockIdx.z;
    const i64 m0 = (i64)blockIdx.y * 128, n0 = (i64)blockIdx.x * 128;
    const int K = p.K;
    const u16* Abh = p.Ah + (i64)z * p.sAz;
    const u16* Abl = p.Al + (i64)z * p.sAz;
    const u16* Bbh = p.Bh + (i64)z * p.sBz;
    const u16* Bbl = p.Bl + (i64)z * p.sBz;
    const int r0 = tid >> 2, kc = (tid & 3) * 8;   // inst0 row, col
    const int r1 = r0 + 64;                        // inst1 row
    u16* dA0 = &Ash[wave * 512];
    u16* dA1 = &Ash[2048 + wave * 512];
    u16* dA0l = &Asl[wave * 512];
    u16* dA1l = &Asl[2048 + wave * 512];
    u16* dB0 = &Bsh[wave * 512];
    u16* dB1 = &Bsh[2048 + wave * 512];
    u16* dB0l = &Bsl[wave * 512];
    u16* dB1l = &Bsl[2048 + wave * 512];
    const int wm = (wave >> 1) * 64, wn = (wave & 1) * 64;
    f32x4 acc[4][4] = {};

    for (int k0 = 0; k0 < K; k0 += 32) {
        __syncthreads();
        const i64 ga0 = (m0 + r0) * K + k0 + kc;
        const i64 ga1 = (m0 + r1) * K + k0 + kc;
        const i64 gb0 = (n0 + r0) * K + k0 + kc;
        const i64 gb1 = (n0 + r1) * K + k0 + kc;
        gload16(Abh + ga0, dA0);  gload16(Abh + ga1, dA1);
        gload16(Abl + ga0, dA0l); gload16(Abl + ga1, dA1l);
        gload16(Bbh + gb0, dB0);  gload16(Bbh + gb1, dB1);
        gload16(Bbl + gb0, dB0l); gload16(Bbl + gb1, dB1l);
        __syncthreads();
        const int fr = lane & 15, fk = (lane >> 4) * 8;
        bf16x8 fah[4], fal[4], fbh[4], fbl[4];
#pragma unroll
        for (int t = 0; t < 4; ++t) {
            fah[t] = *(const bf16x8*)&Ash[(wm + t * 16 + fr) * 32 + fk];
            fal[t] = *(const bf16x8*)&Asl[(wm + t * 16 + fr) * 32 + fk];
            fbh[t] = *(const bf16x8*)&Bsh[(wn + t * 16 + fr) * 32 + fk];
            fbl[t] = *(const bf16x8*)&Bsl[(wn + t * 16 + fr) * 32 + fk];
        }
#pragma unroll
        for (int mi = 0; mi < 4; ++mi)
#pragma unroll
            for (int ni = 0; ni < 4; ++ni) {
                acc[mi][ni] = __builtin_amdgcn_mfma_f32_16x16x32_bf16(fah[mi], fbh[ni], acc[mi][ni], 0, 0, 0);
                acc[mi][ni] = __builtin_amdgcn_mfma_f32_16x16x32_bf16(fah[mi], fbl[ni], acc[mi][ni], 0, 0, 0);
                acc[mi][ni] = __builtin_amdgcn_mfma_f32_16x16x32_bf16(fal[mi], fbh[ni], acc[mi][ni], 0, 0, 0);
            }
    }

    const int fr = lane & 15, fq = (lane >> 4) * 4;
    if (p.mode == 0) {
        float* C = p.Cf + (i64)z * p.sCz;
#pragma unroll
        for (int mi = 0; mi < 4; ++mi)
#pragma unroll
            for (int e = 0; e < 4; ++e) {
                const i64 row = m0 + wm + mi * 16 + fq + e;
#pragma unroll
                for (int ni = 0; ni < 4; ++ni)
                    C[row * p.ldc + n0 + wn + ni * 16 + fr] = acc[mi][ni][e];
            }
    } else if (p.mode == 3) {
        float* C = p.Cf + (i64)z * p.sCz;
        // zero the [i][i+1] holes (never scatter targets; disjoint writes)
        if (n0 == 0 && tid < 128) {
            const int hr = (int)m0 + tid;
            if (hr < SEQ - 1) C[(i64)hr * SEQ + hr + 1] = 0.f;
        }
#pragma unroll
        for (int mi = 0; mi < 4; ++mi)
#pragma unroll
            for (int e = 0; e < 4; ++e) {
                const int r = (int)(m0 + wm + mi * 16 + fq + e);
#pragma unroll
                for (int ni = 0; ni < 4; ++ni) {
                    const int f = (int)n0 + wn + ni * 16 + fr;
                    if (f >= SEQ - 1 - r)
                        C[(i64)r * SEQ + (f + r - (SEQ - 1))] = acc[mi][ni][e];
                    else if (r >= 1)
                        C[(i64)(r - 1) * SEQ + (f + r + 1)] = acc[mi][ni][e];
                }
            }
    } else if (p.mode == 5) {
        float* C = p.Cf + (i64)z * p.sCz;
        const float* M = p.msk;
#pragma unroll
        for (int mi = 0; mi < 4; ++mi)
#pragma unroll
            for (int e = 0; e < 4; ++e) {
                const i64 row = m0 + wm + mi * 16 + fq + e;
#pragma unroll
                for (int ni = 0; ni < 4; ++ni) {
                    const i64 idx = row * p.ldc + n0 + wn + ni * 16 + fr;
                    C[idx] = (acc[mi][ni][e] + C[idx]) * 0.03125f
                             + M[row * SEQ + n0 + wn + ni * 16 + fr];
                }
            }
    } else if (p.mode == 1) {
        const i64 obase = (i64)z * IN_E;
#pragma unroll
        for (int mi = 0; mi < 4; ++mi)
#pragma unroll
            for (int e = 0; e < 4; ++e) {
                const i64 m = m0 + wm + mi * 16 + fq + e;
#pragma unroll
                for (int ni = 0; ni < 4; ++ni) {
                    const int c = (int)n0 + wn + ni * 16 + fr;
                    const int h = c >> 6, d = c & 63;
                    const i64 off = ((i64)h * SEQ + m) * DHEAD + d;
                    float v = acc[mi][ni][e];
                    if (z == 0) v += p.b1[c];
                    const u16 hb = f2bf(v);
                    const u16 lb = f2bf(v - bf2f(hb));
                    p.O1h[obase + off] = hb;
                    p.O1l[obase + off] = lb;
                    if (z == 0) {
                        const float v2 = acc[mi][ni][e] + p.b2[c];
                        const u16 hb2 = f2bf(v2);
                        const u16 lb2 = f2bf(v2 - bf2f(hb2));
                        p.O2h[off] = hb2;
                        p.O2l[off] = lb2;
                    }
                }
            }
    } else { // mode 2: exact GELU
        float* C = p.Cf;
#pragma unroll
        for (int mi = 0; mi < 4; ++mi)
#pragma unroll
            for (int e = 0; e < 4; ++e) {
                const i64 row = m0 + wm + mi * 16 + fq + e;
#pragma unroll
                for (int ni = 0; ni < 4; ++ni) {
                    const float x = acc[mi][ni][e];
                    C[row * p.ldc + n0 + wn + ni * 16 + fr] =
                        0.5f * x * (1.f + erff(x * 0.70710678118654752f));
                }
            }
    }
}

// ---------------------------------------------------------------------------
// PV: O[m, z*64+d] = sum_f W[z][m][f] * V[z][f][d]
// ---------------------------------------------------------------------------
__global__ __launch_bounds__(256)
void mfma_pv(const float* __restrict__ Wgt, const u16* __restrict__ VTh,
             const u16* __restrict__ VTl, u16* __restrict__ Oh, u16* __restrict__ Ol)
{
    __shared__ __align__(16) float Asf[256 * 32];
    __shared__ __align__(16) u16 Bsh[64 * 32];
    __shared__ __align__(16) u16 Bsl[64 * 32];
    const int tid = threadIdx.x, wave = tid >> 6, lane = tid & 63;
    const int z = blockIdx.z;
    const i64 m0 = (i64)blockIdx.y * 256;
    const float* A = Wgt + (i64)z * SEQ * SEQ;
    const u16* Bh = VTh + (i64)z * HEAD_E;
    const u16* Bl = VTl + (i64)z * HEAD_E;
    const int ar = tid >> 3, akc = (tid & 7) * 4;
    const int br = tid >> 2, bkc = (tid & 3) * 8;
    const int wm = wave * 64;
    f32x4 acc[4][4] = {};

    for (int k0 = 0; k0 < SEQ; k0 += 32) {
        __syncthreads();
#pragma unroll
        for (int i = 0; i < 8; ++i)
            gload16(A + (m0 + ar + i * 32) * SEQ + k0 + akc, &Asf[(i * 256 + wave * 64) * 4]);
        gload16(Bh + (i64)br * SEQ + k0 + bkc, &Bsh[wave * 512]);
        gload16(Bl + (i64)br * SEQ + k0 + bkc, &Bsl[wave * 512]);
        __syncthreads();
        const int fr = lane & 15, fk = (lane >> 4) * 8;
        bf16x8 fbh[4], fbl[4];
#pragma unroll
        for (int t = 0; t < 4; ++t) {
            fbh[t] = *(const bf16x8*)&Bsh[(t * 16 + fr) * 32 + fk];
            fbl[t] = *(const bf16x8*)&Bsl[(t * 16 + fr) * 32 + fk];
        }
#pragma unroll
        for (int mi = 0; mi < 4; ++mi) {
            const float4 x0 = *(const float4*)&Asf[(wm + mi * 16 + fr) * 32 + fk];
            const float4 x1 = *(const float4*)&Asf[(wm + mi * 16 + fr) * 32 + fk + 4];
            float av[8] = { x0.x, x0.y, x0.z, x0.w, x1.x, x1.y, x1.z, x1.w };
            bf16x8 ah, al;
#pragma unroll
            for (int j = 0; j < 8; ++j) {
                union { float f; unsigned u; } v; v.f = av[j];
                const u16 hb = (u16)(v.u >> 16);           // chop hi
                union { unsigned u; float f; } fh; fh.u = v.u & 0xFFFF0000u;
                union { float f; unsigned u; } rm; rm.f = av[j] - fh.f;  // exact
                ah[j] = (short)hb;
                al[j] = (short)(u16)(rm.u >> 16);          // chop lo
            }
#pragma unroll
            for (int ni = 0; ni < 4; ++ni) {
                acc[mi][ni] = __builtin_amdgcn_mfma_f32_16x16x32_bf16(ah, fbh[ni], acc[mi][ni], 0, 0, 0);
                acc[mi][ni] = __builtin_amdgcn_mfma_f32_16x16x32_bf16(ah, fbl[ni], acc[mi][ni], 0, 0, 0);
                acc[mi][ni] = __builtin_amdgcn_mfma_f32_16x16x32_bf16(al, fbh[ni], acc[mi][ni], 0, 0, 0);
            }
        }
    }

    const int fr = lane & 15, fq = (lane >> 4) * 4;
#pragma unroll
    for (int mi = 0; mi < 4; ++mi)
#pragma unroll
        for (int e = 0; e < 4; ++e) {
            const i64 m = m0 + wm + mi * 16 + fq + e;
#pragma unroll
            for (int ni = 0; ni < 4; ++ni) {
                const int c = z * 64 + ni * 16 + fr;
                const float v = acc[mi][ni][e];
                const u16 hb = f2bf(v);
                Oh[m * DMODEL + c] = hb;
                Ol[m * DMODEL + c] = f2bf(v - bf2f(hb));
            }
        }
}

// ---------------------------------------------------------------------------
// vv [h][f][d] -> vvT [h][d][f]  (bf16 hi+lo)
// ---------------------------------------------------------------------------
__global__ __launch_bounds__(256)
void transpose_vv(const u16* __restrict__ vh, const u16* __restrict__ vl,
                  u16* __restrict__ th, u16* __restrict__ tl)
{
    __shared__ u16 tile[64][65];
    const int tid = threadIdx.x;
    const int h = blockIdx.y, f0 = blockIdx.x * 64;
    const i64 src = ((i64)h * SEQ + f0) * DHEAD;
    const i64 dst = (i64)h * HEAD_E + f0;
#pragma unroll
    for (int i = 0; i < 16; ++i) {
        const int idx = i * 256 + tid;
        const int r = idx >> 6, c = idx & 63;
        tile[c][r] = vh[src + (i64)r * 64 + c];
    }
    __syncthreads();
#pragma unroll
    for (int i = 0; i < 16; ++i) {
        const int idx = i * 256 + tid;
        const int d = idx >> 6, fl = idx & 63;
        th[dst + (i64)d * SEQ + fl] = tile[d][fl];
    }
    __syncthreads();
#pragma unroll
    for (int i = 0; i < 16; ++i) {
        const int idx = i * 256 + tid;
        const int r = idx >> 6, c = idx & 63;
        tile[c][r] = vl[src + (i64)r * 64 + c];
    }
    __syncthreads();
#pragma unroll
    for (int i = 0; i < 16; ++i) {
        const int idx = i * 256 + tid;
        const int d = idx >> 6, fl = idx & 63;
        tl[dst + (i64)d * SEQ + fl] = tile[d][fl];
    }
}

// ---------------------------------------------------------------------------
// Row softmax, 2-stream: S (finished scores, from mode-5) -> W (normalized).
// Block-per-row, aligned float4 only, shfl+LDS reduce, sharded atomicMin.
// ---------------------------------------------------------------------------
__global__ __launch_bounds__(256)
void softmax_rows(float* __restrict__ Wbase, const float* __restrict__ Sbase,
                  unsigned int* __restrict__ lmin, int h0)
{
    __shared__ float red[4];
    const int hl = blockIdx.y;
    float* Wh = Wbase + (i64)(h0 + hl) * SEQ * SEQ;
    const float* S = Sbase + (i64)hl * SEQ * SEQ;
    const int i = blockIdx.x;
    const int tx = threadIdx.x;
    const i64 rowoff = (i64)i * SEQ;
    float s[8];
    float mloc = -3.0e38f;
#pragma unroll
    for (int r = 0; r < 2; ++r) {
        const int j = (r << 10) + tx * 4;
        const float4 sv = *(const float4*)&S[rowoff + j];
        s[r * 4 + 0] = sv.x; s[r * 4 + 1] = sv.y;
        s[r * 4 + 2] = sv.z; s[r * 4 + 3] = sv.w;
        mloc = fmaxf(mloc, fmaxf(fmaxf(sv.x, sv.y), fmaxf(sv.z, sv.w)));
    }
#pragma unroll
    for (int o = 32; o > 0; o >>= 1) mloc = fmaxf(mloc, __shfl_xor(mloc, o));
    if ((tx & 63) == 0) red[tx >> 6] = mloc;
    __syncthreads();
    const float m = fmaxf(fmaxf(red[0], red[1]), fmaxf(red[2], red[3]));
    __syncthreads();
    float lsum = 0.f;
#pragma unroll
    for (int r = 0; r < 8; ++r) { s[r] = __expf(s[r] - m); lsum += s[r]; }
#pragma unroll
    for (int o = 32; o > 0; o >>= 1) lsum += __shfl_xor(lsum, o);
    if ((tx & 63) == 0) red[tx >> 6] = lsum;
    __syncthreads();
    const float l = red[0] + red[1] + red[2] + red[3];
    const float inv = 1.f / l;
#pragma unroll
    for (int r = 0; r < 2; ++r) {
        const int j = (r << 10) + tx * 4;
        float4 ov;
        ov.x = s[r * 4 + 0] * inv;
        ov.y = s[r * 4 + 1] * inv;
        ov.z = s[r * 4 + 2] * inv;
        ov.w = s[r * 4 + 3] * inv;
        *(float4*)&Wh[rowoff + j] = ov;
    }
    if (tx == 0)
        atomicMin(&lmin[(((h0 + hl) << 6) + (i & (LSLOTS - 1))) * LSTRIDE],
                  __float_as_uint(l));
}

__global__ __launch_bounds__(1024)
void init_kernel(unsigned int* __restrict__ lmin)
{
    lmin[threadIdx.x * LSTRIDE] = 0x7F7FFFFFu;
}

__global__ __launch_bounds__(1024)
void loss_kernel(const unsigned int* __restrict__ lmin, float* __restrict__ out)
{
    __shared__ float hs[16];
    const int w = threadIdx.x >> 6;      // head = wave id
    const int lane = threadIdx.x & 63;   // slot
    float l = __uint_as_float(lmin[threadIdx.x * LSTRIDE]);
#pragma unroll
    for (int o = 32; o > 0; o >>= 1) l = fminf(l, __shfl_xor(l, o));
    if (lane == 0) hs[w] = 1.f / l;
    __syncthreads();
    if (threadIdx.x == 0) {
        float v = 0.f;
#pragma unroll
        for (int h = 0; h < 16; ++h) v += hs[h];
        *out = v * (1.f / NHEADS);
    }
}

// ---------------------------------------------------------------------------
extern "C" void kernel_launch(void* const* d_in, const int* in_sizes, int n_in,
                              void* d_out, int out_size, void* d_ws, size_t ws_size,
                              hipStream_t stream)
{
    const float* query = (const float*)d_in[0];
    const float* key   = (const float*)d_in[1];
    const float* value = (const float*)d_in[2];
    const float* mask  = (const float*)d_in[3];
    const float* Wq    = (const float*)d_in[4];
    const float* Wke   = (const float*)d_in[5];
    const float* Wkr   = (const float*)d_in[6];
    const float* Wv    = (const float*)d_in[7];
    const float* Wf    = (const float*)d_in[8];
    const float* u_p   = (const float*)d_in[9];
    const float* v_p   = (const float*)d_in[10];

    float* out_final = (float*)d_out;
    float* weights   = out_final + (i64)SEQ * DMODEL;
    float* loss      = weights + (i64)NHEADS * SEQ * SEQ;

    // workspace layout
    char* w = (char*)d_ws;
    u16* in_h = (u16*)w;               w += (i64)4 * IN_E * 2;   // [query][key][value][rel]
    u16* in_l = (u16*)w;               w += (i64)4 * IN_E * 2;
    u16* W_h  = (u16*)w;               w += (i64)5 * W_E * 2;    // [Wq][Wke][Wv][Wkr][Wf]
    u16* W_l  = (u16*)w;               w += (i64)5 * W_E * 2;
    u16* P_h  = (u16*)w;               w += (i64)4 * IN_E * 2;   // [qu][kk][vv][rr]
    u16* P_l  = (u16*)w;               w += (i64)4 * IN_E * 2;
    u16* qv_h = (u16*)w;               w += (i64)IN_E * 2;
    u16* qv_l = (u16*)w;               w += (i64)IN_E * 2;
    u16* vvT_h = (u16*)w;              w += (i64)IN_E * 2;
    u16* vvT_l = (u16*)w;              w += (i64)IN_E * 2;
    u16* o_h  = (u16*)w;               w += (i64)IN_E * 2;
    u16* o_l  = (u16*)w;               w += (i64)IN_E * 2;
    unsigned int* lmin = (unsigned int*)w; w += (i64)NHEADS * LSLOTS * LSTRIDE * 4;
    const i64 fixed_bytes = (i64)(w - (char*)d_ws);
    const i64 gbytes = (i64)SEQ * SEQ * 4;
    const i64 avail = (i64)ws_size - fixed_bytes;
    float* G;
    int chunk;
    if (avail >= gbytes) {
        G = (float*)w;
        i64 ch = avail / gbytes;
        chunk = ch > 16 ? 16 : (int)ch;
    } else {
        G = (float*)in_h;   // in-splits dead after projections; 32MB region
        chunk = 2;
    }

    dim3 blk(256);
    init_kernel<<<dim3(1), dim3(1024), 0, stream>>>(lmin);

    // split inputs + weights
    SplitArgs sa;
    sa.src[0] = query; sa.dh[0] = in_h;           sa.dl[0] = in_l;           sa.n4[0] = IN_E / 4;
    sa.src[1] = key;   sa.dh[1] = in_h + IN_E;    sa.dl[1] = in_l + IN_E;    sa.n4[1] = IN_E / 4;
    sa.src[2] = value; sa.dh[2] = in_h + 2*IN_E;  sa.dl[2] = in_l + 2*IN_E;  sa.n4[2] = IN_E / 4;
    sa.src[3] = Wq;    sa.dh[3] = W_h;            sa.dl[3] = W_l;            sa.n4[3] = W_E / 4;
    sa.src[4] = Wke;   sa.dh[4] = W_h + W_E;      sa.dl[4] = W_l + W_E;      sa.n4[4] = W_E / 4;
    sa.src[5] = Wv;    sa.dh[5] = W_h + 2*W_E;    sa.dl[5] = W_l + 2*W_E;    sa.n4[5] = W_E / 4;
    sa.src[6] = Wkr;   sa.dh[6] = W_h + 3*W_E;    sa.dl[6] = W_l + 3*W_E;    sa.n4[6] = W_E / 4;
    sa.src[7] = Wf;    sa.dh[7] = W_h + 4*W_E;    sa.dl[7] = W_l + 4*W_E;    sa.n4[7] = W_E / 4;
    split_all<<<dim3(2048, 8), blk, 0, stream>>>(sa);
    posenc_split<<<dim3(IN_E / 256), blk, 0, stream>>>(in_h + 3*(i64)IN_E, in_l + 3*(i64)IN_E);

    // projections: z in {q,k,v,r}; A stride IN_E, B stride W_E, out stride IN_E
    {
        TNArgs p = {};
        p.Ah = in_h; p.Al = in_l; p.Bh = W_h; p.Bl = W_l;
        p.sAz = IN_E; p.sBz = W_E;
        p.O1h = P_h; p.O1l = P_l; p.O2h = qv_h; p.O2l = qv_l;
        p.b1 = u_p; p.b2 = v_p;
        p.K = DMODEL; p.mode = 1;
        mfma_tn128<<<dim3(DMODEL / 128, SEQ / 128, 4), blk, 0, stream>>>(p);
    }

    transpose_vv<<<dim3(SEQ / 64, NHEADS), blk, 0, stream>>>(
        P_h + 2*(i64)IN_E, P_l + 2*(i64)IN_E, vvT_h, vvT_l);

    // score pipeline per chunk:
    //  1) BD mode-3: pre-shifted scatter -> G (+ hole zeroing)
    //  2) AC mode-5: G = (acc + G)*1/32 + mask  (in-place finished scores)
    //  3) softmax: pure 2-stream S -> weights
    for (int h0 = 0; h0 < NHEADS; h0 += chunk) {
        const int ch = (h0 + chunk <= NHEADS) ? chunk : (NHEADS - h0);
        {
            TNArgs p = {};
            p.Ah = qv_h + (i64)h0 * HEAD_E; p.Al = qv_l + (i64)h0 * HEAD_E;
            p.Bh = P_h + 3*(i64)IN_E + (i64)h0 * HEAD_E;
            p.Bl = P_l + 3*(i64)IN_E + (i64)h0 * HEAD_E;
            p.sAz = HEAD_E; p.sBz = HEAD_E;
            p.Cf = G; p.sCz = (i64)SEQ * SEQ; p.ldc = SEQ;
            p.K = DHEAD; p.mode = 3;
            mfma_tn128<<<dim3(SEQ / 128, SEQ / 128, ch), blk, 0, stream>>>(p);
        }
        {
            TNArgs p = {};
            p.Ah = P_h + (i64)h0 * HEAD_E; p.Al = P_l + (i64)h0 * HEAD_E;          // qu
            p.Bh = P_h + IN_E + (i64)h0 * HEAD_E; p.Bl = P_l + IN_E + (i64)h0 * HEAD_E; // kk
            p.sAz = HEAD_E; p.sBz = HEAD_E;
            p.Cf = G; p.sCz = (i64)SEQ * SEQ; p.ldc = SEQ;
            p.msk = mask;
            p.K = DHEAD; p.mode = 5;
            mfma_tn128<<<dim3(SEQ / 128, SEQ / 128, ch), blk, 0, stream>>>(p);
        }
        softmax_rows<<<dim3(SEQ, ch), blk, 0, stream>>>(weights, G, lmin, h0);
    }

    // PV
    mfma_pv<<<dim3(1, SEQ / 256, NHEADS), blk, 0, stream>>>(weights, vvT_h, vvT_l, o_h, o_l);

    // final GEMM + GELU
    {
        TNArgs p = {};
        p.Ah = o_h; p.Al = o_l;
        p.Bh = W_h + 4*(i64)W_E; p.Bl = W_l + 4*(i64)W_E;
        p.sAz = 0; p.sBz = 0;
        p.Cf = out_final; p.sCz = 0; p.ldc = DMODEL;
        p.K = DMODEL; p.mode = 2;
        mfma_tn128<<<dim3(DMODEL / 128, SEQ / 128, 1), blk, 0, stream>>>(p);
    }

    loss_kernel<<<dim3(1), dim3(1024), 0, stream>>>(lmin, loss);
}

// Round 8
// 566.837 us; speedup vs baseline: 1.3016x; 1.3016x over previous
//
#include <hip/hip_runtime.h>
#include <math.h>

#define SEQ 2048
#define DMODEL 1024
#define NHEADS 16
#define DHEAD 64

// lmin sharding: 64 slices per head, each slice on its own 128B line
#define LSLOTS 64
#define LSTRIDE 32   // uints between slots (128 bytes)

typedef long long i64;
typedef unsigned short u16;
typedef __attribute__((ext_vector_type(4))) float f32x4;
typedef __attribute__((ext_vector_type(8))) short bf16x8;

#define IN_E  2097152   // 2048*1024
#define W_E   1048576   // 1024*1024
#define HEAD_E 131072   // 2048*64

// ---------------------------------------------------------------------------
// bf16 split helpers
// ---------------------------------------------------------------------------
__device__ inline u16 f2bf(float x) {                // RNE
    union { float f; unsigned u; } v; v.f = x;
    unsigned r = v.u + 0x7FFF + ((v.u >> 16) & 1);
    return (u16)(r >> 16);
}
__device__ inline float bf2f(u16 h) {
    union { unsigned u; float f; } v; v.u = ((unsigned)h) << 16;
    return v.f;
}

__device__ inline void gload16(const void* g, void* l) {
    __builtin_amdgcn_global_load_lds(
        (const __attribute__((address_space(1))) unsigned int*)g,
        (__attribute__((address_space(3))) unsigned int*)l, 16, 0, 0);
}

// ---------------------------------------------------------------------------
// Split 8 f32 arrays into bf16 hi/lo. z = array id, float4 per thread.
// ---------------------------------------------------------------------------
struct SplitArgs {
    const float* src[8];
    u16* dh[8];
    u16* dl[8];
    int n4[8];
};
__global__ __launch_bounds__(256)
void split_all(SplitArgs a)
{
    const int z = blockIdx.y;
    const int i = blockIdx.x * 256 + threadIdx.x;
    if (i >= a.n4[z]) return;
    const float4 x = ((const float4*)a.src[z])[i];
    u16 h0 = f2bf(x.x), h1 = f2bf(x.y), h2 = f2bf(x.z), h3 = f2bf(x.w);
    u16 l0 = f2bf(x.x - bf2f(h0)), l1 = f2bf(x.y - bf2f(h1));
    u16 l2 = f2bf(x.z - bf2f(h2)), l3 = f2bf(x.w - bf2f(h3));
    uint2 hh; hh.x = (unsigned)h0 | ((unsigned)h1 << 16); hh.y = (unsigned)h2 | ((unsigned)h3 << 16);
    uint2 ll; ll.x = (unsigned)l0 | ((unsigned)l1 << 16); ll.y = (unsigned)l2 | ((unsigned)l3 << 16);
    ((uint2*)a.dh[z])[i] = hh;
    ((uint2*)a.dl[z])[i] = ll;
}

// ---------------------------------------------------------------------------
// rel_enc computed + split directly (fast-math trig: error << bf16 quantum)
// ---------------------------------------------------------------------------
__global__ __launch_bounds__(256)
void posenc_split(u16* __restrict__ dh, u16* __restrict__ dl)
{
    const int idx = blockIdx.x * 256 + threadIdx.x;
    const int f = idx >> 10;
    const int i = idx & 1023;
    const float P = (float)(SEQ - 1 - f);
    const float ex = (float)(i & ~1) * (1.f / 1024.f);
    const float dv = __expf(ex * -9.210340372f);   // 10000^-ex
    const float ang = P * dv;
    const float val = (i & 1) ? __cosf(ang) : __sinf(ang);
    const u16 hb = f2bf(val);
    dh[idx] = hb;
    dl[idx] = f2bf(val - bf2f(hb));
}

// ---------------------------------------------------------------------------
// Split-3 bf16 MFMA TN GEMM, 128x128 tile, BK=32.
// C = A(MxK) * B(NxK)^T ; A/B pre-split into bf16 hi/lo.
// mode 0: f32 store C[z*sCz + m*ldc + n]
// mode 1: projection epilogue: head-layout split store to O1 (+bias1 if z==0);
//         if z==0 also O2 = acc + bias2 (split).
// mode 2: exact-GELU f32 store
// ---------------------------------------------------------------------------
struct TNArgs {
    const u16 *Ah, *Al, *Bh, *Bl;
    i64 sAz, sBz;
    float* Cf; i64 sCz; int ldc;
    u16 *O1h, *O1l, *O2h, *O2l;
    const float *b1, *b2;
    int K, mode;
};

__global__ __launch_bounds__(256)
void mfma_tn128(TNArgs p)
{
    __shared__ __align__(16) u16 Ash[128 * 32];
    __shared__ __align__(16) u16 Asl[128 * 32];
    __shared__ __align__(16) u16 Bsh[128 * 32];
    __shared__ __align__(16) u16 Bsl[128 * 32];
    const int tid = threadIdx.x, wave = tid >> 6, lane = tid & 63;
    const int z = blockIdx.z;
    const i64 m0 = (i64)blockIdx.y * 128, n0 = (i64)blockIdx.x * 128;
    const int K = p.K;
    const u16* Abh = p.Ah + (i64)z * p.sAz;
    const u16* Abl = p.Al + (i64)z * p.sAz;
    const u16* Bbh = p.Bh + (i64)z * p.sBz;
    const u16* Bbl = p.Bl + (i64)z * p.sBz;
    const int r0 = tid >> 2, kc = (tid & 3) * 8;   // inst0 row, col
    const int r1 = r0 + 64;                        // inst1 row
    u16* dA0 = &Ash[wave * 512];
    u16* dA1 = &Ash[2048 + wave * 512];
    u16* dA0l = &Asl[wave * 512];
    u16* dA1l = &Asl[2048 + wave * 512];
    u16* dB0 = &Bsh[wave * 512];
    u16* dB1 = &Bsh[2048 + wave * 512];
    u16* dB0l = &Bsl[wave * 512];
    u16* dB1l = &Bsl[2048 + wave * 512];
    const int wm = (wave >> 1) * 64, wn = (wave & 1) * 64;
    f32x4 acc[4][4] = {};

    for (int k0 = 0; k0 < K; k0 += 32) {
        __syncthreads();
        const i64 ga0 = (m0 + r0) * K + k0 + kc;
        const i64 ga1 = (m0 + r1) * K + k0 + kc;
        const i64 gb0 = (n0 + r0) * K + k0 + kc;
        const i64 gb1 = (n0 + r1) * K + k0 + kc;
        gload16(Abh + ga0, dA0);  gload16(Abh + ga1, dA1);
        gload16(Abl + ga0, dA0l); gload16(Abl + ga1, dA1l);
        gload16(Bbh + gb0, dB0);  gload16(Bbh + gb1, dB1);
        gload16(Bbl + gb0, dB0l); gload16(Bbl + gb1, dB1l);
        __syncthreads();
        const int fr = lane & 15, fk = (lane >> 4) * 8;
        bf16x8 fah[4], fal[4], fbh[4], fbl[4];
#pragma unroll
        for (int t = 0; t < 4; ++t) {
            fah[t] = *(const bf16x8*)&Ash[(wm + t * 16 + fr) * 32 + fk];
            fal[t] = *(const bf16x8*)&Asl[(wm + t * 16 + fr) * 32 + fk];
            fbh[t] = *(const bf16x8*)&Bsh[(wn + t * 16 + fr) * 32 + fk];
            fbl[t] = *(const bf16x8*)&Bsl[(wn + t * 16 + fr) * 32 + fk];
        }
#pragma unroll
        for (int mi = 0; mi < 4; ++mi)
#pragma unroll
            for (int ni = 0; ni < 4; ++ni) {
                acc[mi][ni] = __builtin_amdgcn_mfma_f32_16x16x32_bf16(fah[mi], fbh[ni], acc[mi][ni], 0, 0, 0);
                acc[mi][ni] = __builtin_amdgcn_mfma_f32_16x16x32_bf16(fah[mi], fbl[ni], acc[mi][ni], 0, 0, 0);
                acc[mi][ni] = __builtin_amdgcn_mfma_f32_16x16x32_bf16(fal[mi], fbh[ni], acc[mi][ni], 0, 0, 0);
            }
    }

    const int fr = lane & 15, fq = (lane >> 4) * 4;
    if (p.mode == 0) {
        float* C = p.Cf + (i64)z * p.sCz;
#pragma unroll
        for (int mi = 0; mi < 4; ++mi)
#pragma unroll
            for (int e = 0; e < 4; ++e) {
                const i64 row = m0 + wm + mi * 16 + fq + e;
#pragma unroll
                for (int ni = 0; ni < 4; ++ni)
                    C[row * p.ldc + n0 + wn + ni * 16 + fr] = acc[mi][ni][e];
            }
    } else if (p.mode == 1) {
        const i64 obase = (i64)z * IN_E;
#pragma unroll
        for (int mi = 0; mi < 4; ++mi)
#pragma unroll
            for (int e = 0; e < 4; ++e) {
                const i64 m = m0 + wm + mi * 16 + fq + e;
#pragma unroll
                for (int ni = 0; ni < 4; ++ni) {
                    const int c = (int)n0 + wn + ni * 16 + fr;
                    const int h = c >> 6, d = c & 63;
                    const i64 off = ((i64)h * SEQ + m) * DHEAD + d;
                    float v = acc[mi][ni][e];
                    if (z == 0) v += p.b1[c];
                    const u16 hb = f2bf(v);
                    const u16 lb = f2bf(v - bf2f(hb));
                    p.O1h[obase + off] = hb;
                    p.O1l[obase + off] = lb;
                    if (z == 0) {
                        const float v2 = acc[mi][ni][e] + p.b2[c];
                        const u16 hb2 = f2bf(v2);
                        const u16 lb2 = f2bf(v2 - bf2f(hb2));
                        p.O2h[off] = hb2;
                        p.O2l[off] = lb2;
                    }
                }
            }
    } else { // mode 2: exact GELU
        float* C = p.Cf;
#pragma unroll
        for (int mi = 0; mi < 4; ++mi)
#pragma unroll
            for (int e = 0; e < 4; ++e) {
                const i64 row = m0 + wm + mi * 16 + fq + e;
#pragma unroll
                for (int ni = 0; ni < 4; ++ni) {
                    const float x = acc[mi][ni][e];
                    C[row * p.ldc + n0 + wn + ni * 16 + fr] =
                        0.5f * x * (1.f + erff(x * 0.70710678118654752f));
                }
            }
    }
}

// ---------------------------------------------------------------------------
// PV: O[m, z*64+d] = sum_f W[z][m][f] * V[z][f][d]
// 64-row strips -> grid 512 blocks (2/CU, full 256-CU coverage; the old
// 256-row strip gave 128 blocks = HALF the GPU idle). Wave owns 16 rows
// (acc[4] over the 64 d-columns). B re-staged per block but vvT is 16 MB
// total -> L2/L3-resident, no extra HBM.
// ---------------------------------------------------------------------------
__global__ __launch_bounds__(256)
void mfma_pv(const float* __restrict__ Wgt, const u16* __restrict__ VTh,
             const u16* __restrict__ VTl, u16* __restrict__ Oh, u16* __restrict__ Ol)
{
    __shared__ __align__(16) float Asf[64 * 32];
    __shared__ __align__(16) u16 Bsh[64 * 32];
    __shared__ __align__(16) u16 Bsl[64 * 32];
    const int tid = threadIdx.x, wave = tid >> 6, lane = tid & 63;
    const int z = blockIdx.z;
    const i64 m0 = (i64)blockIdx.y * 64;
    const float* A = Wgt + (i64)z * SEQ * SEQ;
    const u16* Bh = VTh + (i64)z * HEAD_E;
    const u16* Bl = VTl + (i64)z * HEAD_E;
    const int ar = tid >> 3, akc = (tid & 7) * 4;   // A-stage: row, k-col
    const int br = tid >> 2, bkc = (tid & 3) * 8;
    const int wm = wave * 16;
    f32x4 acc[4] = {};

    for (int k0 = 0; k0 < SEQ; k0 += 32) {
        __syncthreads();
#pragma unroll
        for (int i = 0; i < 2; ++i)
            gload16(A + (m0 + ar + i * 32) * SEQ + k0 + akc, &Asf[(i * 256 + wave * 64) * 4]);
        gload16(Bh + (i64)br * SEQ + k0 + bkc, &Bsh[wave * 512]);
        gload16(Bl + (i64)br * SEQ + k0 + bkc, &Bsl[wave * 512]);
        __syncthreads();
        const int fr = lane & 15, fk = (lane >> 4) * 8;
        bf16x8 fbh[4], fbl[4];
#pragma unroll
        for (int t = 0; t < 4; ++t) {
            fbh[t] = *(const bf16x8*)&Bsh[(t * 16 + fr) * 32 + fk];
            fbl[t] = *(const bf16x8*)&Bsl[(t * 16 + fr) * 32 + fk];
        }
        const float4 x0 = *(const float4*)&Asf[(wm + fr) * 32 + fk];
        const float4 x1 = *(const float4*)&Asf[(wm + fr) * 32 + fk + 4];
        float av[8] = { x0.x, x0.y, x0.z, x0.w, x1.x, x1.y, x1.z, x1.w };
        bf16x8 ah, al;
#pragma unroll
        for (int j = 0; j < 8; ++j) {
            union { float f; unsigned u; } v; v.f = av[j];
            const u16 hb = (u16)(v.u >> 16);           // chop hi
            union { unsigned u; float f; } fh; fh.u = v.u & 0xFFFF0000u;
            union { float f; unsigned u; } rm; rm.f = av[j] - fh.f;  // exact
            ah[j] = (short)hb;
            al[j] = (short)(u16)(rm.u >> 16);          // chop lo
        }
#pragma unroll
        for (int ni = 0; ni < 4; ++ni) {
            acc[ni] = __builtin_amdgcn_mfma_f32_16x16x32_bf16(ah, fbh[ni], acc[ni], 0, 0, 0);
            acc[ni] = __builtin_amdgcn_mfma_f32_16x16x32_bf16(ah, fbl[ni], acc[ni], 0, 0, 0);
            acc[ni] = __builtin_amdgcn_mfma_f32_16x16x32_bf16(al, fbh[ni], acc[ni], 0, 0, 0);
        }
    }

    const int fr = lane & 15, fq = (lane >> 4) * 4;
#pragma unroll
    for (int e = 0; e < 4; ++e) {
        const i64 m = m0 + wm + fq + e;
#pragma unroll
        for (int ni = 0; ni < 4; ++ni) {
            const int c = z * 64 + ni * 16 + fr;
            const float v = acc[ni][e];
            const u16 hb = f2bf(v);
            Oh[m * DMODEL + c] = hb;
            Ol[m * DMODEL + c] = f2bf(v - bf2f(hb));
        }
    }
}

// ---------------------------------------------------------------------------
// vv [h][f][d] -> vvT [h][d][f]  (bf16 hi+lo)
// ---------------------------------------------------------------------------
__global__ __launch_bounds__(256)
void transpose_vv(const u16* __restrict__ vh, const u16* __restrict__ vl,
                  u16* __restrict__ th, u16* __restrict__ tl)
{
    __shared__ u16 tile[64][65];
    const int tid = threadIdx.x;
    const int h = blockIdx.y, f0 = blockIdx.x * 64;
    const i64 src = ((i64)h * SEQ + f0) * DHEAD;
    const i64 dst = (i64)h * HEAD_E + f0;
#pragma unroll
    for (int i = 0; i < 16; ++i) {
        const int idx = i * 256 + tid;
        const int r = idx >> 6, c = idx & 63;
        tile[c][r] = vh[src + (i64)r * 64 + c];
    }
    __syncthreads();
#pragma unroll
    for (int i = 0; i < 16; ++i) {
        const int idx = i * 256 + tid;
        const int d = idx >> 6, fl = idx & 63;
        th[dst + (i64)d * SEQ + fl] = tile[d][fl];
    }
    __syncthreads();
#pragma unroll
    for (int i = 0; i < 16; ++i) {
        const int idx = i * 256 + tid;
        const int r = idx >> 6, c = idx & 63;
        tile[c][r] = vl[src + (i64)r * 64 + c];
    }
    __syncthreads();
#pragma unroll
    for (int i = 0; i < 16; ++i) {
        const int idx = i * 256 + tid;
        const int d = idx >> 6, fl = idx & 63;
        tl[dst + (i64)d * SEQ + fl] = tile[d][fl];
    }
}

// ---------------------------------------------------------------------------
// Row softmax (round-1 structure: block-per-row, 8 elems/thread, shfl+LDS
// reduce, sharded atomicMin). G unshifted; 3-branch gather emulates shift.
// Best measured softmax variant (175 us); r3/r4 restructures were slower.
// ---------------------------------------------------------------------------
__global__ __launch_bounds__(256)
void softmax_rows(float* __restrict__ Wbase, const float* __restrict__ Gbase,
                  const float* __restrict__ mask, unsigned int* __restrict__ lmin, int h0)
{
    __shared__ float red[4];
    const int hl = blockIdx.y;
    float* Wh = Wbase + (i64)(h0 + hl) * SEQ * SEQ;
    const float* G = Gbase + (i64)hl * SEQ * SEQ;
    const int i = blockIdx.x;
    const int tx = threadIdx.x;
    const i64 rowoff = (i64)i * SEQ;
    float s[8];
    float mloc = -3.0e38f;
#pragma unroll
    for (int r = 0; r < 8; ++r) {
        const int j = tx + (r << 8);
        float bd;
        if (j <= i)          bd = G[rowoff + (SEQ - 1 - i + j)];
        else if (j == i + 1) bd = 0.f;
        else                 bd = G[rowoff + SEQ + (j - i - 2)];
        const float v = (Wh[rowoff + j] + bd) * 0.03125f + mask[rowoff + j];
        s[r] = v;
        mloc = fmaxf(mloc, v);
    }
#pragma unroll
    for (int o = 32; o > 0; o >>= 1) mloc = fmaxf(mloc, __shfl_xor(mloc, o));
    if ((tx & 63) == 0) red[tx >> 6] = mloc;
    __syncthreads();
    const float m = fmaxf(fmaxf(red[0], red[1]), fmaxf(red[2], red[3]));
    __syncthreads();
    float lsum = 0.f;
#pragma unroll
    for (int r = 0; r < 8; ++r) { s[r] = __expf(s[r] - m); lsum += s[r]; }
#pragma unroll
    for (int o = 32; o > 0; o >>= 1) lsum += __shfl_xor(lsum, o);
    if ((tx & 63) == 0) red[tx >> 6] = lsum;
    __syncthreads();
    const float l = red[0] + red[1] + red[2] + red[3];
    const float inv = 1.f / l;
#pragma unroll
    for (int r = 0; r < 8; ++r) Wh[rowoff + tx + (r << 8)] = s[r] * inv;
    if (tx == 0)
        atomicMin(&lmin[(((h0 + hl) << 6) + (i & (LSLOTS - 1))) * LSTRIDE],
                  __float_as_uint(l));
}

__global__ __launch_bounds__(1024)
void init_kernel(unsigned int* __restrict__ lmin)
{
    lmin[threadIdx.x * LSTRIDE] = 0x7F7FFFFFu;
}

__global__ __launch_bounds__(1024)
void loss_kernel(const unsigned int* __restrict__ lmin, float* __restrict__ out)
{
    __shared__ float hs[16];
    const int w = threadIdx.x >> 6;      // head = wave id
    const int lane = threadIdx.x & 63;   // slot
    float l = __uint_as_float(lmin[threadIdx.x * LSTRIDE]);
#pragma unroll
    for (int o = 32; o > 0; o >>= 1) l = fminf(l, __shfl_xor(l, o));
    if (lane == 0) hs[w] = 1.f / l;
    __syncthreads();
    if (threadIdx.x == 0) {
        float v = 0.f;
#pragma unroll
        for (int h = 0; h < 16; ++h) v += hs[h];
        *out = v * (1.f / NHEADS);
    }
}

// ---------------------------------------------------------------------------
extern "C" void kernel_launch(void* const* d_in, const int* in_sizes, int n_in,
                              void* d_out, int out_size, void* d_ws, size_t ws_size,
                              hipStream_t stream)
{
    const float* query = (const float*)d_in[0];
    const float* key   = (const float*)d_in[1];
    const float* value = (const float*)d_in[2];
    const float* mask  = (const float*)d_in[3];
    const float* Wq    = (const float*)d_in[4];
    const float* Wke   = (const float*)d_in[5];
    const float* Wkr   = (const float*)d_in[6];
    const float* Wv    = (const float*)d_in[7];
    const float* Wf    = (const float*)d_in[8];
    const float* u_p   = (const float*)d_in[9];
    const float* v_p   = (const float*)d_in[10];

    float* out_final = (float*)d_out;
    float* weights   = out_final + (i64)SEQ * DMODEL;
    float* loss      = weights + (i64)NHEADS * SEQ * SEQ;

    // workspace layout
    char* w = (char*)d_ws;
    u16* in_h = (u16*)w;               w += (i64)4 * IN_E * 2;   // [query][key][value][rel]
    u16* in_l = (u16*)w;               w += (i64)4 * IN_E * 2;
    u16* W_h  = (u16*)w;               w += (i64)5 * W_E * 2;    // [Wq][Wke][Wv][Wkr][Wf]
    u16* W_l  = (u16*)w;               w += (i64)5 * W_E * 2;
    u16* P_h  = (u16*)w;               w += (i64)4 * IN_E * 2;   // [qu][kk][vv][rr]
    u16* P_l  = (u16*)w;               w += (i64)4 * IN_E * 2;
    u16* qv_h = (u16*)w;               w += (i64)IN_E * 2;
    u16* qv_l = (u16*)w;               w += (i64)IN_E * 2;
    u16* vvT_h = (u16*)w;              w += (i64)IN_E * 2;
    u16* vvT_l = (u16*)w;              w += (i64)IN_E * 2;
    u16* o_h  = (u16*)w;               w += (i64)IN_E * 2;
    u16* o_l  = (u16*)w;               w += (i64)IN_E * 2;
    unsigned int* lmin = (unsigned int*)w; w += (i64)NHEADS * LSLOTS * LSTRIDE * 4;
    const i64 fixed_bytes = (i64)(w - (char*)d_ws);
    const i64 gbytes = (i64)SEQ * SEQ * 4;
    const i64 avail = (i64)ws_size - fixed_bytes;
    float* G;
    int chunk;
    if (avail >= gbytes) {
        G = (float*)w;
        i64 ch = avail / gbytes;
        chunk = ch > 16 ? 16 : (int)ch;
    } else {
        G = (float*)in_h;   // in-splits dead after projections; 32MB region
        chunk = 2;
    }

    dim3 blk(256);
    init_kernel<<<dim3(1), dim3(1024), 0, stream>>>(lmin);

    // split inputs + weights
    SplitArgs sa;
    sa.src[0] = query; sa.dh[0] = in_h;           sa.dl[0] = in_l;           sa.n4[0] = IN_E / 4;
    sa.src[1] = key;   sa.dh[1] = in_h + IN_E;    sa.dl[1] = in_l + IN_E;    sa.n4[1] = IN_E / 4;
    sa.src[2] = value; sa.dh[2] = in_h + 2*IN_E;  sa.dl[2] = in_l + 2*IN_E;  sa.n4[2] = IN_E / 4;
    sa.src[3] = Wq;    sa.dh[3] = W_h;            sa.dl[3] = W_l;            sa.n4[3] = W_E / 4;
    sa.src[4] = Wke;   sa.dh[4] = W_h + W_E;      sa.dl[4] = W_l + W_E;      sa.n4[4] = W_E / 4;
    sa.src[5] = Wv;    sa.dh[5] = W_h + 2*W_E;    sa.dl[5] = W_l + 2*W_E;    sa.n4[5] = W_E / 4;
    sa.src[6] = Wkr;   sa.dh[6] = W_h + 3*W_E;    sa.dl[6] = W_l + 3*W_E;    sa.n4[6] = W_E / 4;
    sa.src[7] = Wf;    sa.dh[7] = W_h + 4*W_E;    sa.dl[7] = W_l + 4*W_E;    sa.n4[7] = W_E / 4;
    split_all<<<dim3(2048, 8), blk, 0, stream>>>(sa);
    posenc_split<<<dim3(IN_E / 256), blk, 0, stream>>>(in_h + 3*(i64)IN_E, in_l + 3*(i64)IN_E);

    // projections: z in {q,k,v,r}; A stride IN_E, B stride W_E, out stride IN_E
    {
        TNArgs p = {};
        p.Ah = in_h; p.Al = in_l; p.Bh = W_h; p.Bl = W_l;
        p.sAz = IN_E; p.sBz = W_E;
        p.O1h = P_h; p.O1l = P_l; p.O2h = qv_h; p.O2l = qv_l;
        p.b1 = u_p; p.b2 = v_p;
        p.K = DMODEL; p.mode = 1;
        mfma_tn128<<<dim3(DMODEL / 128, SEQ / 128, 4), blk, 0, stream>>>(p);
    }

    transpose_vv<<<dim3(SEQ / 64, NHEADS), blk, 0, stream>>>(
        P_h + 2*(i64)IN_E, P_l + 2*(i64)IN_E, vvT_h, vvT_l);

    // AC, all heads -> raw scores into weights region
    {
        TNArgs p = {};
        p.Ah = P_h; p.Al = P_l;                       // qu
        p.Bh = P_h + IN_E; p.Bl = P_l + IN_E;         // kk
        p.sAz = HEAD_E; p.sBz = HEAD_E;
        p.Cf = weights; p.sCz = (i64)SEQ * SEQ; p.ldc = SEQ;
        p.K = DHEAD; p.mode = 0;
        mfma_tn128<<<dim3(SEQ / 128, SEQ / 128, NHEADS), blk, 0, stream>>>(p);
    }

    // G + softmax in chunks
    for (int h0 = 0; h0 < NHEADS; h0 += chunk) {
        const int ch = (h0 + chunk <= NHEADS) ? chunk : (NHEADS - h0);
        TNArgs p = {};
        p.Ah = qv_h + (i64)h0 * HEAD_E; p.Al = qv_l + (i64)h0 * HEAD_E;
        p.Bh = P_h + 3*(i64)IN_E + (i64)h0 * HEAD_E;
        p.Bl = P_l + 3*(i64)IN_E + (i64)h0 * HEAD_E;
        p.sAz = HEAD_E; p.sBz = HEAD_E;
        p.Cf = G; p.sCz = (i64)SEQ * SEQ; p.ldc = SEQ;
        p.K = DHEAD; p.mode = 0;
        mfma_tn128<<<dim3(SEQ / 128, SEQ / 128, ch), blk, 0, stream>>>(p);
        softmax_rows<<<dim3(SEQ, ch), blk, 0, stream>>>(weights, G, mask, lmin, h0);
    }

    // PV (64-row strips: 512 blocks, full CU coverage)
    mfma_pv<<<dim3(1, SEQ / 64, NHEADS), blk, 0, stream>>>(weights, vvT_h, vvT_l, o_h, o_l);

    // final GEMM + GELU
    {
        TNArgs p = {};
        p.Ah = o_h; p.Al = o_l;
        p.Bh = W_h + 4*(i64)W_E; p.Bl = W_l + 4*(i64)W_E;
        p.sAz = 0; p.sBz = 0;
        p.Cf = out_final; p.sCz = 0; p.ldc = DMODEL;
        p.K = DMODEL; p.mode = 2;
        mfma_tn128<<<dim3(DMODEL / 128, SEQ / 128, 1), blk, 0, stream>>>(p);
    }

    loss_kernel<<<dim3(1), dim3(1024), 0, stream>>>(lmin, loss);
}